// Round 1
// 511.451 us; speedup vs baseline: 1.0696x; 1.0696x over previous
//
#include <hip/hip_runtime.h>

#define DIM 128
#define NCB 8
#define KSZ 2048
#define BATCH 16
#define TOK 2048
#define NTOK (BATCH * TOK)            // 32768
#define NELEM (BATCH * DIM * TOK)     // 4194304
#define T_TILE 64                     // tokens per block
#define NTHR 256                      // 4 waves
#define CHUNK 64
#define NCHUNK (KSZ / CHUNK)          // 32

typedef float f32x4 __attribute__((ext_vector_type(4)));
typedef short s16x8 __attribute__((ext_vector_type(8)));

__device__ __forceinline__ unsigned short f2bf(float f) {
    unsigned u = __float_as_uint(f);
    u = (u + 0x7FFFu + ((u >> 16) & 1u)) >> 16;   // RNE, finite inputs only
    return (unsigned short)u;
}
__device__ __forceinline__ float bf2f(unsigned short h) {
    return __uint_as_float(((unsigned)h) << 16);
}

// ---------------------------------------------------------------------------
// prep: codebooks -> bf16 hi plane only (lh pass needs only B_hi)
// ---------------------------------------------------------------------------
__global__ void rvq_prep_hi(const float* __restrict__ cbs,
                            unsigned short* __restrict__ ch) {
    int i = blockIdx.x * 256 + threadIdx.x;
    ch[i] = f2bf(cbs[i]);
}

// ---------------------------------------------------------------------------
// exact fp32 cnorm + zero loss accumulator
// ---------------------------------------------------------------------------
__global__ void rvq_cnorm(const float* __restrict__ cbs,
                          float* __restrict__ cnorm,
                          float* __restrict__ loss_acc) {
    if (blockIdx.x == 0 && threadIdx.x == 0) *loss_acc = 0.0f;
    int k = blockIdx.x * 256 + threadIdx.x;
    const float4* row = (const float4*)(cbs + (size_t)k * DIM);
    float s = 0.0f;
#pragma unroll
    for (int i = 0; i < DIM / 4; ++i) {
        float4 v = row[i];
        s += v.x * v.x + v.y * v.y + v.z * v.z + v.w * v.w;
    }
    cnorm[k] = s;
}

// ---------------------------------------------------------------------------
// fused RVQ, 4 waves/block, 2 blocks/CU (LDS 78.3 KB). Approx scores:
// 2-pass split-bf16 MFMA (hh + lh = r * c_hi); per-lane min4-over-nt +
// running top-2; parallel quad-merge (4 thr/token, shfl) -> exact fp32
// rescore of global top-4. Residual LDS-resident across stages.
// ---------------------------------------------------------------------------
__global__ __launch_bounds__(NTHR, 2) void rvq_fused(
        const float* __restrict__ x,            // (B, D, T)
        const float* __restrict__ cbs,          // (NCB, KSZ, DIM) fp32
        const unsigned short* __restrict__ ch,  // bf16 hi
        const float* __restrict__ cng,          // (NCB*KSZ) exact cnorm
        float* __restrict__ out,                // (B, D, T)
        float* __restrict__ codes,              // (B, NCB, T) as float
        float* __restrict__ loss_acc) {
    __shared__ float res_lds[T_TILE][DIM + 2];     // 33280 B
    __shared__ unsigned short Bbuf[2][8192];       // 2 x 16 KB (hi only)
    __shared__ float mv1[T_TILE * 16];             // 4 KB
    __shared__ float mv2[T_TILE * 16];             // 4 KB
    __shared__ unsigned short mi1[T_TILE * 16];    // 2 KB
    __shared__ unsigned short mi2[T_TILE * 16];    // 2 KB  => 78336 B total

    const int tid   = threadIdx.x;
    const int lane  = tid & 63;
    const int wv    = __builtin_amdgcn_readfirstlane(tid >> 6);  // 0..3
    const int col16 = lane & 15;
    const int quad  = lane >> 4;

    const int token0 = blockIdx.x * T_TILE;
    const int b      = token0 >> 11;
    const int t_in_b = token0 & (TOK - 1);

    // ---- init: x[b][d][t0..] -> res_lds[t][d] ----
    {
        const float* xb = x + (size_t)b * DIM * TOK + t_in_b;
#pragma unroll
        for (int it = 0; it < 8; ++it) {
            int idx = it * NTHR + tid;           // 0..2047
            int d  = idx >> 4;
            int t4 = (idx & 15) * 4;
            float4 v = *(const float4*)(xb + (size_t)d * TOK + t4);
            res_lds[t4 + 0][d] = v.x;
            res_lds[t4 + 1][d] = v.y;
            res_lds[t4 + 2][d] = v.z;
            res_lds[t4 + 3][d] = v.w;
        }
    }
    __syncthreads();

    float my_loss = 0.0f;

// staging: wave wv owns frags f = wv*4 .. wv*4+3 (f = rowgrp*4 + dimchunk)
#define STAGE_PREFETCH(cc)                                                     \
    {                                                                          \
        const unsigned short* _p = ch_s +                                      \
            ((size_t)((cc) * CHUNK + wv * 16 + col16)) * DIM + quad * 8;       \
        stg0 = *(const s16x8*)(_p + 0);                                        \
        stg1 = *(const s16x8*)(_p + 32);                                       \
        stg2 = *(const s16x8*)(_p + 64);                                       \
        stg3 = *(const s16x8*)(_p + 96);                                       \
    }

#define STAGE_WRITE(buf)                                                       \
    {                                                                          \
        *(s16x8*)&Bbuf[buf][(wv * 4 + 0) * 512 + lane * 8] = stg0;             \
        *(s16x8*)&Bbuf[buf][(wv * 4 + 1) * 512 + lane * 8] = stg1;             \
        *(s16x8*)&Bbuf[buf][(wv * 4 + 2) * 512 + lane * 8] = stg2;             \
        *(s16x8*)&Bbuf[buf][(wv * 4 + 3) * 512 + lane * 8] = stg3;             \
    }

#define COMPUTE(accv, buf)                                                     \
    {                                                                          \
        _Pragma("unroll")                                                      \
        for (int nt = 0; nt < 4; ++nt) accv[nt] = (f32x4){0.f, 0.f, 0.f, 0.f}; \
        _Pragma("unroll")                                                      \
        for (int dc = 0; dc < 4; ++dc) {                                       \
            s16x8 bh0 = *(const s16x8*)&Bbuf[buf][(0 + dc) * 512 + lane * 8];  \
            s16x8 bh1 = *(const s16x8*)&Bbuf[buf][(4 + dc) * 512 + lane * 8];  \
            s16x8 bh2 = *(const s16x8*)&Bbuf[buf][(8 + dc) * 512 + lane * 8];  \
            s16x8 bh3 = *(const s16x8*)&Bbuf[buf][(12 + dc) * 512 + lane * 8]; \
            accv[0] = __builtin_amdgcn_mfma_f32_16x16x32_bf16(ah[dc], bh0, accv[0], 0, 0, 0); \
            accv[1] = __builtin_amdgcn_mfma_f32_16x16x32_bf16(ah[dc], bh1, accv[1], 0, 0, 0); \
            accv[2] = __builtin_amdgcn_mfma_f32_16x16x32_bf16(ah[dc], bh2, accv[2], 0, 0, 0); \
            accv[3] = __builtin_amdgcn_mfma_f32_16x16x32_bf16(ah[dc], bh3, accv[3], 0, 0, 0); \
            accv[0] = __builtin_amdgcn_mfma_f32_16x16x32_bf16(al[dc], bh0, accv[0], 0, 0, 0); \
            accv[1] = __builtin_amdgcn_mfma_f32_16x16x32_bf16(al[dc], bh1, accv[1], 0, 0, 0); \
            accv[2] = __builtin_amdgcn_mfma_f32_16x16x32_bf16(al[dc], bh2, accv[2], 0, 0, 0); \
            accv[3] = __builtin_amdgcn_mfma_f32_16x16x32_bf16(al[dc], bh3, accv[3], 0, 0, 0); \
        }                                                                      \
    }

// fold chunk cc's scores (approx score = cnorm - 2*dot; rn constant/token)
#define FOLD(accv, cc)                                                         \
    {                                                                          \
        int _ib0 = (cc) * CHUNK + col16;                                       \
        float _cn0 = cn_s[_ib0], _cn1 = cn_s[_ib0 + 16];                       \
        float _cn2 = cn_s[_ib0 + 32], _cn3 = cn_s[_ib0 + 48];                  \
        _Pragma("unroll")                                                      \
        for (int r = 0; r < 4; ++r) {                                          \
            float p0 = fmaf(-2.0f, accv[0][r], _cn0);                          \
            float p1 = fmaf(-2.0f, accv[1][r], _cn1);                          \
            float p2 = fmaf(-2.0f, accv[2][r], _cn2);                          \
            float p3 = fmaf(-2.0f, accv[3][r], _cn3);                          \
            bool c01 = p1 < p0;                                                \
            float m01 = c01 ? p1 : p0; int j01 = c01 ? _ib0 + 16 : _ib0;       \
            bool c23 = p3 < p2;                                                \
            float m23 = c23 ? p3 : p2; int j23 = c23 ? _ib0 + 48 : _ib0 + 32;  \
            bool cf = m23 < m01;                                               \
            float m = cf ? m23 : m01; int jm = cf ? j23 : j01;                 \
            bool b1 = m < v1[r];                                               \
            bool b2 = m < v2[r];                                               \
            v2[r] = b1 ? v1[r] : (b2 ? m : v2[r]);                             \
            i2[r] = b1 ? i1[r] : (b2 ? jm : i2[r]);                            \
            v1[r] = b1 ? m : v1[r];                                            \
            i1[r] = b1 ? jm : i1[r];                                           \
        }                                                                      \
    }

#pragma unroll 1
    for (int s = 0; s < NCB; ++s) {
        const unsigned short* __restrict__ ch_s = ch  + (size_t)s * KSZ * DIM;
        const float* __restrict__ cb_s = cbs + (size_t)s * KSZ * DIM;
        const float* __restrict__ cn_s = cng + (size_t)s * KSZ;

        // ---- A fragments (hi+lo) from LDS residual; wave owns 16 tokens ----
        s16x8 ah[4], al[4];
#pragma unroll
        for (int dc = 0; dc < 4; ++dc) {
            int t  = wv * 16 + col16;
            int d0 = dc * 32 + quad * 8;
            float4 u = *(const float4*)&res_lds[t][d0];
            float4 w = *(const float4*)&res_lds[t][d0 + 4];
            float e[8] = {u.x, u.y, u.z, u.w, w.x, w.y, w.z, w.w};
            s16x8 hv, lv;
#pragma unroll
            for (int j = 0; j < 8; ++j) {
                unsigned short h = f2bf(e[j]);
                hv[j] = (short)h;
                lv[j] = (short)f2bf(e[j] - bf2f(h));
            }
            ah[dc] = hv;
            al[dc] = lv;
        }

        float v1[4], v2[4]; int i1[4], i2[4];
#pragma unroll
        for (int r = 0; r < 4; ++r) {
            v1[r] = 3.4e38f; v2[r] = 3.4e38f; i1[r] = 0; i2[r] = 0;
        }

        s16x8 stg0, stg1, stg2, stg3;
        f32x4 accA[4], accB[4];

        // ---- pipelined chunk sweep ----
        STAGE_PREFETCH(0); STAGE_WRITE(0); __syncthreads();
        STAGE_PREFETCH(1);
        COMPUTE(accA, 0);
        STAGE_WRITE(1); __syncthreads();
#pragma unroll 1
        for (int c = 1; c < 31; c += 2) {
            STAGE_PREFETCH(c + 1);
            COMPUTE(accB, 1);
            FOLD(accA, c - 1);
            STAGE_WRITE(0);
            __syncthreads();
            STAGE_PREFETCH(c + 2);
            COMPUTE(accA, 0);
            FOLD(accB, c);
            STAGE_WRITE(1);
            __syncthreads();
        }
        COMPUTE(accB, 1);
        FOLD(accA, 30);
        FOLD(accB, 31);

        // ---- publish per-lane top-2 ----
#pragma unroll
        for (int r = 0; r < 4; ++r) {
            int t = wv * 16 + quad * 4 + r;
            mv1[t * 16 + col16] = v1[r];
            mi1[t * 16 + col16] = (unsigned short)i1[r];
            mv2[t * 16 + col16] = v2[r];
            mi2[t * 16 + col16] = (unsigned short)i2[r];
        }
        __syncthreads();

        // ---- parallel merge: 4 thr/token, 8 cands each, quad shfl-merge ----
        const int t  = tid >> 2;
        const int cs = tid & 3;
        float bv[4] = {3.4e38f, 3.4e38f, 3.4e38f, 3.4e38f};
        int   bi[4] = {0x7FFFFFFF, 0x7FFFFFFF, 0x7FFFFFFF, 0x7FFFFFFF};
        {
            const float4 cv1 = *(const float4*)&mv1[tid * 4];
            const float4 cv2 = *(const float4*)&mv2[tid * 4];
            const unsigned short* ci1 = &mi1[tid * 4];
            const unsigned short* ci2 = &mi2[tid * 4];
            float vv[8] = {cv1.x, cv1.y, cv1.z, cv1.w,
                           cv2.x, cv2.y, cv2.z, cv2.w};
            int   ii[8] = {ci1[0], ci1[1], ci1[2], ci1[3],
                           ci2[0], ci2[1], ci2[2], ci2[3]};
#pragma unroll
            for (int c = 0; c < 8; ++c) {
                float v = vv[c]; int i = ii[c];
#pragma unroll
                for (int j = 0; j < 4; ++j) {
                    if (v < bv[j] || (v == bv[j] && i < bi[j])) {
                        float tv = bv[j]; bv[j] = v; v = tv;
                        int   ti = bi[j]; bi[j] = i; i = ti;
                    }
                }
            }
#pragma unroll
            for (int mk = 1; mk <= 2; mk <<= 1) {
                float ov[4]; int oi[4];
#pragma unroll
                for (int j = 0; j < 4; ++j) {
                    ov[j] = __shfl_xor(bv[j], mk, 64);
                    oi[j] = __shfl_xor(bi[j], mk, 64);
                }
#pragma unroll
                for (int c = 0; c < 4; ++c) {
                    float v = ov[c]; int i = oi[c];
#pragma unroll
                    for (int j = 0; j < 4; ++j) {
                        if (v < bv[j] || (v == bv[j] && i < bi[j])) {
                            float tv = bv[j]; bv[j] = v; v = tv;
                            int   ti = bi[j]; bi[j] = i; i = ti;
                        }
                    }
                }
            }
        }
        // all 4 quad lanes hold identical sorted top-4; lane cs takes slot cs
        const int cand = (cs == 0) ? bi[0]
                       : (cs == 1) ? bi[1]
                       : (cs == 2) ? bi[2] : bi[3];

        // ---- exact fp32 rescore: 4 threads per token, 1 candidate each ----
        {
            const float* crow = cb_s + (size_t)cand * DIM;
            float n0 = 0, n1 = 0, n2 = 0, n3 = 0;
            float a0 = 0, a1 = 0, a2 = 0, a3 = 0;
#pragma unroll 8
            for (int d4 = 0; d4 < DIM / 4; ++d4) {
                float4 r4 = *(const float4*)&res_lds[t][d4 * 4];
                float4 q4 = *(const float4*)&crow[d4 * 4];
                n0 = fmaf(r4.x, r4.x, n0); n1 = fmaf(r4.y, r4.y, n1);
                n2 = fmaf(r4.z, r4.z, n2); n3 = fmaf(r4.w, r4.w, n3);
                a0 = fmaf(r4.x, q4.x, a0); a1 = fmaf(r4.y, q4.y, a1);
                a2 = fmaf(r4.z, q4.z, a2); a3 = fmaf(r4.w, q4.w, a3);
            }
            float rn  = (n0 + n1) + (n2 + n3);
            float dot = (a0 + a1) + (a2 + a3);
            float dist = fmaf(-2.0f, dot, rn) + cn_s[cand];
            int best = cand;
#pragma unroll
            for (int mk = 1; mk <= 2; mk <<= 1) {
                float od = __shfl_xor(dist, mk, 64);
                int   oi = __shfl_xor(best, mk, 64);
                if (od < dist || (od == dist && oi < best)) {
                    dist = od; best = oi;
                }
            }
            if (cs == 0)
                codes[(size_t)b * (NCB * TOK) + (size_t)s * TOK + t_in_b + t] =
                    (float)best;
            // update my 32-dim slice of the token's residual + loss partial
            const float* qrow = cb_s + (size_t)best * DIM;
            float lp = 0.0f;
#pragma unroll
            for (int d4 = 0; d4 < 8; ++d4) {
                int d = cs * 32 + d4 * 4;
                float4 r4 = *(const float4*)&res_lds[t][d];
                float4 q4 = *(const float4*)&qrow[d];
                float4 nr;
                nr.x = r4.x - q4.x; nr.y = r4.y - q4.y;
                nr.z = r4.z - q4.z; nr.w = r4.w - q4.w;
                *(float4*)&res_lds[t][d] = nr;
                lp += nr.x * nr.x + nr.y * nr.y + nr.z * nr.z + nr.w * nr.w;
            }
            my_loss += lp;
        }
        __syncthreads();
    }

    // ---- epilogue: out[b][d][t] = x - residual ----
    {
        const float* xb = x + (size_t)b * DIM * TOK + t_in_b;
        float* ob = out + (size_t)b * DIM * TOK + t_in_b;
#pragma unroll
        for (int it = 0; it < 8; ++it) {
            int idx = it * NTHR + tid;
            int d  = idx >> 4;
            int t4 = (idx & 15) * 4;
            float4 v = *(const float4*)(xb + (size_t)d * TOK + t4);
            float4 o;
            o.x = v.x - res_lds[t4 + 0][d];
            o.y = v.y - res_lds[t4 + 1][d];
            o.z = v.z - res_lds[t4 + 2][d];
            o.w = v.w - res_lds[t4 + 3][d];
            *(float4*)(ob + (size_t)d * TOK + t4) = o;
        }
    }

    // ---- loss reduction ----
#pragma unroll
    for (int off = 32; off > 0; off >>= 1)
        my_loss += __shfl_down(my_loss, off, 64);
    if (lane == 0) atomicAdd(loss_acc, my_loss);
}

// ---------------------------------------------------------------------------
__global__ void rvq_loss_fin(const float* __restrict__ loss_acc,
                             float* __restrict__ loss_out) {
    *loss_out = *loss_acc * (1.0f / (float)NELEM);
}

// ---------------------------------------------------------------------------
extern "C" void kernel_launch(void* const* d_in, const int* in_sizes, int n_in,
                              void* d_out, int out_size, void* d_ws, size_t ws_size,
                              hipStream_t stream) {
    const float* x   = (const float*)d_in[0];   // (B, D, T)
    const float* cbs = (const float*)d_in[1];   // (NCB, KSZ, DIM)

    float* out      = (float*)d_out;
    float* codes    = out + NELEM;
    float* loss_out = out + NELEM + (size_t)BATCH * NCB * TOK;

    float* wsf      = (float*)d_ws;
    float* loss_acc = wsf;
    unsigned short* ch = (unsigned short*)(wsf + 256);
    float* cng = (float*)(ch + (size_t)NCB * KSZ * DIM);

    hipLaunchKernelGGL(rvq_prep_hi, dim3((NCB * KSZ * DIM) / 256), dim3(256),
                       0, stream, cbs, ch);
    hipLaunchKernelGGL(rvq_cnorm, dim3((NCB * KSZ) / 256), dim3(256), 0, stream,
                       cbs, cng, loss_acc);
    hipLaunchKernelGGL(rvq_fused, dim3(NTOK / T_TILE), dim3(NTHR), 0, stream,
                       x, cbs, ch, cng, out, codes, loss_acc);
    hipLaunchKernelGGL(rvq_loss_fin, dim3(1), dim3(1), 0, stream,
                       loss_acc, loss_out);
}